// Round 1
// baseline (413.071 us; speedup 1.0000x reference)
//
#include <hip/hip_runtime.h>
#include <hip/hip_bf16.h>

#define N_NODES 50000
#define N_EDGES 800000
#define BROW 264   // padded LDS row stride in us (528 B -> 2-way-free b128 reads)

typedef __attribute__((ext_vector_type(8))) short bfrag8;   // 8 bf16 (4 VGPRs)
typedef __attribute__((ext_vector_type(4))) float f32x4;
typedef __attribute__((ext_vector_type(4))) unsigned short us4;
typedef __attribute__((ext_vector_type(8))) unsigned short us8;

__device__ __forceinline__ float bf2f(unsigned short u) {
  return __uint_as_float(((unsigned int)u) << 16);
}
__device__ __forceinline__ unsigned short f2bf(float f) {
  unsigned int u = __float_as_uint(f);
  u = (u + 0x7fffu + ((u >> 16) & 1u)) >> 16;
  return (unsigned short)u;
}
__device__ __forceinline__ float ldS(const void* p, int f32, size_t i) {
  return f32 ? ((const float*)p)[i] : bf2f(((const unsigned short*)p)[i]);
}
__device__ __forceinline__ void stO(void* out, int f32, int i, float v) {
  if (f32) ((float*)out)[i] = v;
  else ((unsigned short*)out)[i] = f2bf(v);
}

// Stage 64 rows x 256 cols of src into LDS as bf16 with 512 threads:
// thread t -> row t>>3, 32-col chunk t&7 (4 x us8 per thread).
template <int F32>
__device__ __forceinline__ void stageB8(const void* src, int nb,
                                        unsigned short* __restrict__ Bs) {
  const int t = threadIdx.x;
  const int r = t >> 3;
  const int q = t & 7;
  int row = nb + r;
  row = row < N_NODES ? row : (N_NODES - 1);
  const size_t base = (size_t)row * 256 + q * 32;
  unsigned short* dst = Bs + r * BROW + q * 32;
  if (F32) {
    const f32x4* s4 = (const f32x4*)((const float*)src + base);
#pragma unroll
    for (int j = 0; j < 4; ++j) {
      f32x4 a = s4[2 * j], b = s4[2 * j + 1];
      us8 o;
      o[0] = f2bf(a[0]); o[1] = f2bf(a[1]); o[2] = f2bf(a[2]); o[3] = f2bf(a[3]);
      o[4] = f2bf(b[0]); o[5] = f2bf(b[1]); o[6] = f2bf(b[2]); o[7] = f2bf(b[3]);
      *(us8*)(dst + j * 8) = o;
    }
  } else {
    const us8* s8 = (const us8*)((const unsigned short*)src + base);
#pragma unroll
    for (int j = 0; j < 4; ++j) *(us8*)(dst + j * 8) = s8[j];
  }
}

// flags: 0=x_is_f32 1=ea_is_f32 2=uf_is_f32 3=W_is_f32 4=idx_is_i64 5=out_is_f32
__global__ void k_detect(const void* x, const void* ea, const void* uf,
                         const void* f1W, const int* ei, int* flags) {
  int lane = threadIdx.x & 63;
  unsigned short ux = ((const unsigned short*)x)[lane];
  unsigned short ue = ((const unsigned short*)ea)[lane];
  unsigned short uu = ((const unsigned short*)uf)[lane];
  unsigned short uw = ((const unsigned short*)f1W)[lane];
  int oi = ei[2 * lane + 1];
  unsigned long long bx = __ballot(((ux >> 7) & 0xFF) > 0x85);
  unsigned long long be = __ballot((ue & 0x8000u) != 0);
  unsigned long long bu = __ballot(((uu >> 7) & 0xFF) > 0x85);
  unsigned long long bw = __ballot(((uw >> 7) & 0xFF) > 0x7E);
  unsigned long long bi = __ballot(oi != 0);
  if (lane == 0) {
    int fx = bx ? 1 : 0, fe = be ? 1 : 0, fu = bu ? 1 : 0, fw = bw ? 1 : 0;
    flags[0] = fx; flags[1] = fe; flags[2] = fu; flags[3] = fw;
    flags[4] = (bi == 0ull) ? 1 : 0;
    flags[5] = (fx & fe & fu & fw);
  }
}

// Zero the atomic targets of the edge pass.
__global__ __launch_bounds__(256) void k_zero3(int* __restrict__ counts,
                                               float* __restrict__ degf,
                                               float* __restrict__ mlpc) {
  int i = blockIdx.x * 256 + threadIdx.x;
  if (i < N_NODES) { counts[i] = 0; degf[i] = 0.f; mlpc[i] = 0.f; }
  if (i == 0) counts[N_NODES] = 0;
}

// Single 800k pass: dst histogram + weighted degree, both via atomics.
__global__ __launch_bounds__(256) void k_edges2(const int* __restrict__ ei,
                                                const void* ea,
                                                const int* __restrict__ flags,
                                                int* __restrict__ counts,
                                                float* __restrict__ degf) {
  int e = blockIdx.x * 256 + threadIdx.x;
  if (e >= N_EDGES) return;
  int d;
  if (flags[4]) d = ei[1600000 + 2 * e];
  else          d = ei[800000 + e];
  d = d < 0 ? 0 : (d > N_NODES - 1 ? N_NODES - 1 : d);
  float w = ldS(ea, flags[1], e);
  atomicAdd(&counts[d], 1);
  atomicAdd(&degf[d], w);
}

__global__ __launch_bounds__(256) void k_scan1(const int* __restrict__ cnt,
                                               int* __restrict__ rp,
                                               int* __restrict__ bsum) {
  __shared__ int sd[256];
  int t = threadIdx.x;
  int i0 = blockIdx.x * 1024 + t * 4;
  int v0 = (i0 + 0) < N_NODES ? cnt[i0 + 0] : 0;
  int v1 = (i0 + 1) < N_NODES ? cnt[i0 + 1] : 0;
  int v2 = (i0 + 2) < N_NODES ? cnt[i0 + 2] : 0;
  int v3 = (i0 + 3) < N_NODES ? cnt[i0 + 3] : 0;
  int ts = v0 + v1 + v2 + v3;
  sd[t] = ts;
  __syncthreads();
  for (int off = 1; off < 256; off <<= 1) {
    int x = (t >= off) ? sd[t - off] : 0;
    __syncthreads();
    sd[t] += x;
    __syncthreads();
  }
  int exoff = sd[t] - ts;
  if (i0 + 0 < N_NODES) rp[i0 + 0] = exoff;
  if (i0 + 1 < N_NODES) rp[i0 + 1] = exoff + v0;
  if (i0 + 2 < N_NODES) rp[i0 + 2] = exoff + v0 + v1;
  if (i0 + 3 < N_NODES) rp[i0 + 3] = exoff + v0 + v1 + v2;
  if (t == 255) bsum[blockIdx.x] = sd[255];
}

__global__ void k_scan2(const int* __restrict__ bsum, int* __restrict__ boff,
                        int* __restrict__ rp, int nb) {
  if (threadIdx.x == 0) {
    int run = 0;
    for (int b = 0; b < nb; ++b) { boff[b] = run; run += bsum[b]; }
    rp[N_NODES] = run;
  }
}

// Finalize rowptr + cursor, and fold dinv = rsqrt(deg+1) (self-loop weight 1).
__global__ __launch_bounds__(256) void k_scan3d(int* __restrict__ rp,
                                                const int* __restrict__ boff,
                                                int* __restrict__ cursor,
                                                const float* __restrict__ degf,
                                                float* __restrict__ dinv) {
  int i = blockIdx.x * 256 + threadIdx.x;
  if (i < N_NODES) {
    int r = rp[i] + boff[i >> 10];
    rp[i] = r;
    cursor[i] = r;
    dinv[i] = rsqrtf(degf[i] + 1.0f);
  }
}

// CSR scatter: ONE packed 8B store per edge {src, ew*dinv[src]} -> halves the
// random dirty-line count vs two 4B stores into separate arrays.
__global__ __launch_bounds__(256) void k_place2(const int* __restrict__ ei,
                                                const void* ea,
                                                const int* __restrict__ flags,
                                                const float* __restrict__ dinv,
                                                int* __restrict__ cursor,
                                                unsigned long long* __restrict__ e8) {
  int e = blockIdx.x * 256 + threadIdx.x;
  if (e >= N_EDGES) return;
  int s, d;
  if (flags[4]) { s = ei[2 * e]; d = ei[1600000 + 2 * e]; }
  else          { s = ei[e];     d = ei[800000 + e]; }
  s = s < 0 ? 0 : (s > N_NODES - 1 ? N_NODES - 1 : s);
  d = d < 0 ? 0 : (d > N_NODES - 1 ? N_NODES - 1 : d);
  float w = ldS(ea, flags[1], e) * dinv[s];
  int pos = atomicAdd(&cursor[d], 1);
  e8[pos] = ((unsigned long long)__float_as_uint(w) << 32) | (unsigned int)s;
}

// Merged: blocks 0..287 transpose W1T/WgT; block 288 computes folded head vectors.
__global__ __launch_bounds__(512) void k_prep(
    const void* f1W, const void* g1W, const void* f2W, const void* f2b,
    const void* g2W, const void* g2b, const void* ffW, const void* ffb,
    const int* __restrict__ flags, unsigned short* __restrict__ W1T,
    unsigned short* __restrict__ WgT, float* __restrict__ w2f,
    float* __restrict__ w2g, float* __restrict__ constv) {
  const int fw = flags[3];
  if (blockIdx.x < 288) {
    int tid = blockIdx.x * 512 + threadIdx.x;
    if (tid < 512 * 256) {
      int c = tid >> 8, k = tid & 255;
      W1T[tid] = f2bf(ldS(f1W, fw, (size_t)k * 512 + c));
    } else if (tid < 512 * 256 + 64 * 256) {
      int j = tid - 512 * 256;
      int c = j >> 8, k = j & 255;
      WgT[j] = f2bf(ldS(g1W, fw, (size_t)k * 64 + c));
    }
    return;
  }
  int t = threadIdx.x;
  if (t < 512) {
    float s = 0.f;
    for (int c = 0; c < 64; ++c) s += ldS(f2W, fw, t * 64 + c) * ldS(ffW, fw, c);
    w2f[t] = s;
  }
  if (t < 64) {
    float s = 0.f;
    for (int c = 0; c < 64; ++c) s += ldS(g2W, fw, t * 64 + c) * ldS(ffW, fw, 64 + c);
    w2g[t] = s;
  }
  if (t == 0) {
    float s = ldS(ffb, fw, 0);
    for (int c = 0; c < 64; ++c) {
      s += ldS(f2b, fw, c) * ldS(ffW, fw, c);
      s += ldS(g2b, fw, c) * ldS(ffW, fw, 64 + c);
    }
    constv[0] = s;
  }
}

// ---------------------------------------------------------------------------
// h1b = x @ gcn1_W. 512 threads / 8 waves per 64-node block: wave w owns
// c-tile (w&3)*16 x node-half (w>>2)*32 (acc 8 regs). Runtime-uniform flag
// branch picks the stage path (one launch instead of two).
// ---------------------------------------------------------------------------
__global__ __launch_bounds__(512, 2) void k_h13u(
    const void* x, const unsigned short* __restrict__ WgT,
    const int* __restrict__ flags, unsigned short* __restrict__ h1b) {
  __shared__ unsigned short Bs[64 * BROW];
  const int nb = blockIdx.x * 64;
  if (flags[0]) stageB8<1>(x, nb, Bs);
  else          stageB8<0>(x, nb, Bs);
  __syncthreads();

  const int lane = threadIdx.x & 63;
  const int wave = threadIdx.x >> 6;
  const int ct = wave & 3;        // c-tile (16 cols)
  const int nh = wave >> 2;       // node half (32 nodes)
  const int l15 = lane & 15;
  const int quad = lane >> 4;
  const unsigned short* ap = WgT + (size_t)(ct * 16 + l15) * 256 + quad * 8;

  f32x4 acc[2];
  acc[0] = (f32x4){0.f, 0.f, 0.f, 0.f};
  acc[1] = (f32x4){0.f, 0.f, 0.f, 0.f};

#pragma unroll
  for (int ks = 0; ks < 8; ++ks) {
    bfrag8 a = *(const bfrag8*)(ap + ks * 32);
    const int bofs = ks * 32 + quad * 8;
#pragma unroll
    for (int u = 0; u < 2; ++u) {
      bfrag8 b = *(const bfrag8*)(Bs + (nh * 32 + u * 16 + l15) * BROW + bofs);
      acc[u] = __builtin_amdgcn_mfma_f32_16x16x32_bf16(a, b, acc[u], 0, 0, 0);
    }
  }
#pragma unroll
  for (int u = 0; u < 2; ++u) {
    int node = nb + nh * 32 + u * 16 + l15;
    if (node < N_NODES) {
      us4 o;
#pragma unroll
      for (int r = 0; r < 4; ++r) o[r] = f2bf(acc[u][r]);
      *(us4*)(h1b + (size_t)node * 64 + ct * 16 + quad * 4) = o;
    }
  }
}

// ---------------------------------------------------------------------------
// mlpc = folded MLP branch. 512 threads / 8 waves per 64-node block:
// wave w owns c-slice [w*64, +64) x all 64 nodes (acc 64 regs, single pass).
// 6256 waves total (2x the old 4-wave version) for latency hiding.
// __launch_bounds__(512,2): 256-reg allocator budget (same as old (256,2)) ->
// compiler lands at 128 VGPR, no scratch spill (R7's 93-µs bug).
// ---------------------------------------------------------------------------
__global__ __launch_bounds__(512, 2) void k_mlpu(
    const void* uf, const unsigned short* __restrict__ W1T,
    const void* fc1b, const float* __restrict__ w2f,
    const int* __restrict__ flags, float* __restrict__ mlpc) {
  __shared__ unsigned short Bs[64 * BROW];
  const int nb = blockIdx.x * 64;
  if (flags[2]) stageB8<1>(uf, nb, Bs);
  else          stageB8<0>(uf, nb, Bs);
  __syncthreads();

  const int fw = flags[3];
  const int lane = threadIdx.x & 63;
  const int wave = threadIdx.x >> 6;
  const int l15 = lane & 15;
  const int quad = lane >> 4;
  const int c_base = wave * 64;
  const unsigned short* ap = W1T + (size_t)(c_base + l15) * 256 + quad * 8;

  f32x4 acc[4][4];
#pragma unroll
  for (int t = 0; t < 4; ++t)
#pragma unroll
    for (int u = 0; u < 4; ++u) acc[t][u] = (f32x4){0.f, 0.f, 0.f, 0.f};

#pragma unroll
  for (int ks = 0; ks < 8; ++ks) {
    const int bofs = ks * 32 + quad * 8;
    bfrag8 b[4];
#pragma unroll
    for (int u = 0; u < 4; ++u)
      b[u] = *(const bfrag8*)(Bs + (u * 16 + l15) * BROW + bofs);
#pragma unroll
    for (int t = 0; t < 4; ++t) {
      bfrag8 a = *(const bfrag8*)(ap + (size_t)t * 16 * 256 + ks * 32);
#pragma unroll
      for (int u = 0; u < 4; ++u)
        acc[t][u] = __builtin_amdgcn_mfma_f32_16x16x32_bf16(a, b[u], acc[t][u], 0, 0, 0);
    }
  }

  float part[4] = {0.f, 0.f, 0.f, 0.f};
#pragma unroll
  for (int t = 0; t < 4; ++t) {
#pragma unroll
    for (int r = 0; r < 4; ++r) {
      const int c = c_base + t * 16 + quad * 4 + r;
      const float bc = ldS(fc1b, fw, c);
      const float wc = w2f[c];
#pragma unroll
      for (int u = 0; u < 4; ++u) {
        float v = acc[t][u][r] + bc;
        v = v > 0.f ? v : 0.f;
        part[u] += v * wc;
      }
    }
  }
#pragma unroll
  for (int u = 0; u < 4; ++u) {
    part[u] += __shfl_xor(part[u], 16, 64);
    part[u] += __shfl_xor(part[u], 32, 64);
    int node = nb + u * 16 + l15;
    if (lane < 16 && node < N_NODES) atomicAdd(&mlpc[node], part[u]);
  }
}

// Fused layer-1 aggregation + layer-2 input projection (8-edge unroll, e8 CSR).
__global__ __launch_bounds__(256) void k_aggs2(
    const int* __restrict__ rp, const unsigned long long* __restrict__ e8,
    const unsigned short* __restrict__ h1b, const float* __restrict__ dinv,
    const void* g1b, const float* __restrict__ w2g,
    const int* __restrict__ flags, float* __restrict__ s2) {
  const int i = blockIdx.x * 4 + (threadIdx.x >> 6);
  if (i >= N_NODES) return;
  const int lane = threadIdx.x & 63;
  const int base = rp[i], end = rp[i + 1];
  const float di = dinv[i];
  float acc = 0.f;
  int j = base;
  for (; j + 8 <= end; j += 8) {
    unsigned long long vv[8];
#pragma unroll
    for (int q = 0; q < 8; ++q) vv[q] = e8[j + q];
    float ww[8], hv[8];
#pragma unroll
    for (int q = 0; q < 8; ++q) {
      ww[q] = __uint_as_float((unsigned int)(vv[q] >> 32));
      hv[q] = bf2f(h1b[(size_t)(unsigned int)vv[q] * 64 + lane]);
    }
#pragma unroll
    for (int q = 0; q < 8; ++q) acc += ww[q] * hv[q];
  }
  for (; j < end; ++j) {
    unsigned long long v = e8[j];
    acc += __uint_as_float((unsigned int)(v >> 32)) *
           bf2f(h1b[(size_t)(unsigned int)v * 64 + lane]);
  }
  float v = acc * di + di * di * bf2f(h1b[(size_t)i * 64 + lane]) + ldS(g1b, flags[3], lane);
  v = v > 0.f ? v : 0.f;
  float p = v * w2g[lane];
#pragma unroll
  for (int off = 32; off > 0; off >>= 1) p += __shfl_xor(p, off, 64);
  if (lane == 0) s2[i] = p;
}

// Fused layer-2 aggregation + final output (e8 CSR).
__global__ __launch_bounds__(256) void k_fin2(
    const int* __restrict__ rp, const unsigned long long* __restrict__ e8,
    const float* __restrict__ s2, const float* __restrict__ dinv,
    const float* __restrict__ mlpc, const float* __restrict__ constv,
    const int* __restrict__ flags, void* out) {
  const int i = blockIdx.x * 4 + (threadIdx.x >> 6);
  if (i >= N_NODES) return;
  const int lane = threadIdx.x & 63;
  const int base = rp[i], end = rp[i + 1];
  float p = 0.f;
  for (int j = base + lane; j < end; j += 64) {
    unsigned long long v = e8[j];
    p += __uint_as_float((unsigned int)(v >> 32)) * s2[(unsigned int)v];
  }
#pragma unroll
  for (int off = 32; off > 0; off >>= 1) p += __shfl_xor(p, off, 64);
  if (lane == 0) {
    float di = dinv[i];
    stO(out, flags[5], i, mlpc[i] + di * p + di * di * s2[i] + constv[0]);
  }
}

__global__ __launch_bounds__(256) void k_zero(const int* __restrict__ flags, void* out) {
  int i = blockIdx.x * 256 + threadIdx.x;
  if (i < N_NODES) stO(out, flags[5], i, 0.f);
}

extern "C" void kernel_launch(void* const* d_in, const int* in_sizes, int n_in,
                              void* d_out, int out_size, void* d_ws, size_t ws_size,
                              hipStream_t stream) {
  const void* x   = d_in[0];
  const int*  ei  = (const int*)d_in[1];
  const void* ea  = d_in[2];
  const void* uf  = d_in[3];
  const void* g1W = d_in[4];
  const void* g1b = d_in[5];
  const void* g2W = d_in[6];
  const void* g2b = d_in[7];
  const void* f1W = d_in[8];
  const void* f1b = d_in[9];
  const void* f2W = d_in[10];
  const void* f2b = d_in[11];
  const void* ffW = d_in[12];
  const void* ffb = d_in[13];

  float* ws = (float*)d_ws;
  int*   flags  = (int*)ws;                 // 16
  float* w2f    = ws + 16;                  // 512
  float* w2g    = ws + 528;                 // 64
  float* constv = ws + 592;                 // 16
  float* dinv   = ws + 608;                 // 50,000
  float* degf   = ws + 50608;               // 50,000 (dead after scan3d)
  float* s2     = ws + 50608;               // 50,000 (overlay: live from aggs2)
  float* mlpc   = ws + 100608;              // 50,000
  unsigned short* W1T = (unsigned short*)(ws + 150608);  // 131,072 us
  unsigned short* WgT = W1T + 131072;                    // 16,384 us
  int* rowptr = (int*)(ws + 224336);        // 50,001 (pad 16)
  int* bsum   = (int*)(ws + 274352);        // 64
  int* boff   = bsum + 64;                  // 64
  int* counts = (int*)(ws + 274480);        // 50,016
  int* cursor = (int*)(ws + 324496);        // 50,000
  unsigned long long* e8 = (unsigned long long*)(ws + 374496); // 800,000 x 8B
  unsigned short* h1b = (unsigned short*)(ws + 1974496); // 3.2M us
  const size_t NEED = (size_t)3574496 * 4;  // ~14.3 MB

  k_detect<<<1, 64, 0, stream>>>(x, ea, uf, f1W, ei, flags);
  if (ws_size < NEED) {
    k_zero<<<(N_NODES + 255) / 256, 256, 0, stream>>>(flags, d_out);
    return;
  }
  const int NZB = (N_NODES + 255) / 256;    // 196
  const int NB  = (N_NODES + 1023) / 1024;  // 49
  const int NGB = (N_NODES + 63) / 64;      // 782
  const int NEB = (N_EDGES + 255) / 256;    // 3125

  k_zero3<<<NZB, 256, 0, stream>>>(counts, degf, mlpc);
  k_edges2<<<NEB, 256, 0, stream>>>(ei, ea, flags, counts, degf);
  k_scan1<<<NB, 256, 0, stream>>>(counts, rowptr, bsum);
  k_scan2<<<1, 64, 0, stream>>>(bsum, boff, rowptr, NB);
  k_scan3d<<<NZB, 256, 0, stream>>>(rowptr, boff, cursor, degf, dinv);
  k_place2<<<NEB, 256, 0, stream>>>(ei, ea, flags, dinv, cursor, e8);
  k_prep<<<289, 512, 0, stream>>>(f1W, g1W, f2W, f2b, g2W, g2b, ffW, ffb, flags,
                                  W1T, WgT, w2f, w2g, constv);
  k_h13u<<<NGB, 512, 0, stream>>>(x, WgT, flags, h1b);
  k_mlpu<<<NGB, 512, 0, stream>>>(uf, W1T, f1b, w2f, flags, mlpc);
  k_aggs2<<<(N_NODES + 3) / 4, 256, 0, stream>>>(rowptr, e8, h1b, dinv, g1b, w2g, flags, s2);
  k_fin2<<<(N_NODES + 3) / 4, 256, 0, stream>>>(rowptr, e8, s2, dinv, mlpc, constv, flags, d_out);
}

// Round 2
// 360.259 us; speedup vs baseline: 1.1466x; 1.1466x over previous
//
#include <hip/hip_runtime.h>
#include <hip/hip_bf16.h>

#define N_NODES 50000
#define N_EDGES 800000
#define BROW 264   // padded LDS row stride in us (528 B -> 2-way-free b128 reads)

typedef __attribute__((ext_vector_type(8))) short bfrag8;   // 8 bf16 (4 VGPRs)
typedef __attribute__((ext_vector_type(4))) float f32x4;
typedef __attribute__((ext_vector_type(4))) unsigned short us4;
typedef __attribute__((ext_vector_type(8))) unsigned short us8;

__device__ __forceinline__ float bf2f(unsigned short u) {
  return __uint_as_float(((unsigned int)u) << 16);
}
__device__ __forceinline__ unsigned short f2bf(float f) {
  unsigned int u = __float_as_uint(f);
  u = (u + 0x7fffu + ((u >> 16) & 1u)) >> 16;
  return (unsigned short)u;
}
__device__ __forceinline__ float ldS(const void* p, int f32, size_t i) {
  return f32 ? ((const float*)p)[i] : bf2f(((const unsigned short*)p)[i]);
}
__device__ __forceinline__ void stO(void* out, int f32, int i, float v) {
  if (f32) ((float*)out)[i] = v;
  else ((unsigned short*)out)[i] = f2bf(v);
}

// Stage 64 rows x 256 cols of src into LDS as bf16 with 512 threads:
// thread t -> row t>>3, 32-col chunk t&7 (4 x us8 per thread).
template <int F32>
__device__ __forceinline__ void stageB8(const void* src, int nb,
                                        unsigned short* __restrict__ Bs) {
  const int t = threadIdx.x;
  const int r = t >> 3;
  const int q = t & 7;
  int row = nb + r;
  row = row < N_NODES ? row : (N_NODES - 1);
  const size_t base = (size_t)row * 256 + q * 32;
  unsigned short* dst = Bs + r * BROW + q * 32;
  if (F32) {
    const f32x4* s4 = (const f32x4*)((const float*)src + base);
#pragma unroll
    for (int j = 0; j < 4; ++j) {
      f32x4 a = s4[2 * j], b = s4[2 * j + 1];
      us8 o;
      o[0] = f2bf(a[0]); o[1] = f2bf(a[1]); o[2] = f2bf(a[2]); o[3] = f2bf(a[3]);
      o[4] = f2bf(b[0]); o[5] = f2bf(b[1]); o[6] = f2bf(b[2]); o[7] = f2bf(b[3]);
      *(us8*)(dst + j * 8) = o;
    }
  } else {
    const us8* s8 = (const us8*)((const unsigned short*)src + base);
#pragma unroll
    for (int j = 0; j < 4; ++j) *(us8*)(dst + j * 8) = s8[j];
  }
}

// flags: 0=x_is_f32 1=ea_is_f32 2=uf_is_f32 3=W_is_f32 4=idx_is_i64 5=out_is_f32
__global__ void k_detect(const void* x, const void* ea, const void* uf,
                         const void* f1W, const int* ei, int* flags) {
  int lane = threadIdx.x & 63;
  unsigned short ux = ((const unsigned short*)x)[lane];
  unsigned short ue = ((const unsigned short*)ea)[lane];
  unsigned short uu = ((const unsigned short*)uf)[lane];
  unsigned short uw = ((const unsigned short*)f1W)[lane];
  int oi = ei[2 * lane + 1];
  unsigned long long bx = __ballot(((ux >> 7) & 0xFF) > 0x85);
  unsigned long long be = __ballot((ue & 0x8000u) != 0);
  unsigned long long bu = __ballot(((uu >> 7) & 0xFF) > 0x85);
  unsigned long long bw = __ballot(((uw >> 7) & 0xFF) > 0x7E);
  unsigned long long bi = __ballot(oi != 0);
  if (lane == 0) {
    int fx = bx ? 1 : 0, fe = be ? 1 : 0, fu = bu ? 1 : 0, fw = bw ? 1 : 0;
    flags[0] = fx; flags[1] = fe; flags[2] = fu; flags[3] = fw;
    flags[4] = (bi == 0ull) ? 1 : 0;
    flags[5] = (fx & fe & fu & fw);
  }
}

// Zero the histogram.
__global__ __launch_bounds__(256) void k_zeroc(int* __restrict__ counts) {
  int i = blockIdx.x * 256 + threadIdx.x;
  if (i <= N_NODES) counts[i] = 0;
}

// Histogram of dst + record each edge's within-segment position (the atomic's
// return value). ONE fabric atomic per edge; posw write is coalesced.
__global__ __launch_bounds__(256) void k_histpos(const int* __restrict__ ei,
                                                 const int* __restrict__ flags,
                                                 int* __restrict__ counts,
                                                 int* __restrict__ posw) {
  int e = blockIdx.x * 256 + threadIdx.x;
  if (e >= N_EDGES) return;
  int d;
  if (flags[4]) d = ei[1600000 + 2 * e];
  else          d = ei[800000 + e];
  d = d < 0 ? 0 : (d > N_NODES - 1 ? N_NODES - 1 : d);
  posw[e] = atomicAdd(&counts[d], 1);
}

__global__ __launch_bounds__(256) void k_scan1(const int* __restrict__ cnt,
                                               int* __restrict__ rp,
                                               int* __restrict__ bsum) {
  __shared__ int sd[256];
  int t = threadIdx.x;
  int i0 = blockIdx.x * 1024 + t * 4;
  int v0 = (i0 + 0) < N_NODES ? cnt[i0 + 0] : 0;
  int v1 = (i0 + 1) < N_NODES ? cnt[i0 + 1] : 0;
  int v2 = (i0 + 2) < N_NODES ? cnt[i0 + 2] : 0;
  int v3 = (i0 + 3) < N_NODES ? cnt[i0 + 3] : 0;
  int ts = v0 + v1 + v2 + v3;
  sd[t] = ts;
  __syncthreads();
  for (int off = 1; off < 256; off <<= 1) {
    int x = (t >= off) ? sd[t - off] : 0;
    __syncthreads();
    sd[t] += x;
    __syncthreads();
  }
  int exoff = sd[t] - ts;
  if (i0 + 0 < N_NODES) rp[i0 + 0] = exoff;
  if (i0 + 1 < N_NODES) rp[i0 + 1] = exoff + v0;
  if (i0 + 2 < N_NODES) rp[i0 + 2] = exoff + v0 + v1;
  if (i0 + 3 < N_NODES) rp[i0 + 3] = exoff + v0 + v1 + v2;
  if (t == 255) bsum[blockIdx.x] = sd[255];
}

__global__ void k_scan2(const int* __restrict__ bsum, int* __restrict__ boff,
                        int* __restrict__ rp, int nb) {
  if (threadIdx.x == 0) {
    int run = 0;
    for (int b = 0; b < nb; ++b) { boff[b] = run; run += bsum[b]; }
    rp[N_NODES] = run;
  }
}

__global__ __launch_bounds__(256) void k_scan3(int* __restrict__ rp,
                                               const int* __restrict__ boff) {
  int i = blockIdx.x * 256 + threadIdx.x;
  if (i < N_NODES) rp[i] += boff[i >> 10];
}

// Atomic-free CSR scatter: pos = rowptr[d] + posw[e]. Stores RAW weight
// packed with src: {w:hi32, s:lo32} in one 8B store.
__global__ __launch_bounds__(256) void k_placeb(const int* __restrict__ ei,
                                                const void* ea,
                                                const int* __restrict__ flags,
                                                const int* __restrict__ rp,
                                                const int* __restrict__ posw,
                                                unsigned long long* __restrict__ e8) {
  int e = blockIdx.x * 256 + threadIdx.x;
  if (e >= N_EDGES) return;
  int s, d;
  if (flags[4]) { s = ei[2 * e]; d = ei[1600000 + 2 * e]; }
  else          { s = ei[e];     d = ei[800000 + e]; }
  s = s < 0 ? 0 : (s > N_NODES - 1 ? N_NODES - 1 : s);
  d = d < 0 ? 0 : (d > N_NODES - 1 ? N_NODES - 1 : d);
  float w = ldS(ea, flags[1], e);
  int pos = rp[d] + posw[e];
  e8[pos] = ((unsigned long long)__float_as_uint(w) << 32) | (unsigned int)s;
}

// Weighted degree via coalesced CSR walk; dinv = rsqrt(deg + 1) (self-loop).
__global__ __launch_bounds__(256) void k_degc(const int* __restrict__ rp,
                                              const unsigned long long* __restrict__ e8,
                                              float* __restrict__ dinv) {
  const int i = blockIdx.x * 4 + (threadIdx.x >> 6);
  if (i >= N_NODES) return;
  const int lane = threadIdx.x & 63;
  const int base = rp[i], end = rp[i + 1];
  float s = 0.f;
  for (int j = base + lane; j < end; j += 64)
    s += __uint_as_float((unsigned int)(e8[j] >> 32));
#pragma unroll
  for (int off = 32; off > 0; off >>= 1) s += __shfl_xor(s, off, 64);
  if (lane == 0) dinv[i] = rsqrtf(s + 1.0f);
}

// Merged: blocks 0..287 transpose W1T/WgT; block 288 computes folded head vectors.
__global__ __launch_bounds__(512) void k_prep(
    const void* f1W, const void* g1W, const void* f2W, const void* f2b,
    const void* g2W, const void* g2b, const void* ffW, const void* ffb,
    const int* __restrict__ flags, unsigned short* __restrict__ W1T,
    unsigned short* __restrict__ WgT, float* __restrict__ w2f,
    float* __restrict__ w2g, float* __restrict__ constv) {
  const int fw = flags[3];
  if (blockIdx.x < 288) {
    int tid = blockIdx.x * 512 + threadIdx.x;
    if (tid < 512 * 256) {
      int c = tid >> 8, k = tid & 255;
      W1T[tid] = f2bf(ldS(f1W, fw, (size_t)k * 512 + c));
    } else if (tid < 512 * 256 + 64 * 256) {
      int j = tid - 512 * 256;
      int c = j >> 8, k = j & 255;
      WgT[j] = f2bf(ldS(g1W, fw, (size_t)k * 64 + c));
    }
    return;
  }
  int t = threadIdx.x;
  if (t < 512) {
    float s = 0.f;
    for (int c = 0; c < 64; ++c) s += ldS(f2W, fw, t * 64 + c) * ldS(ffW, fw, c);
    w2f[t] = s;
  }
  if (t < 64) {
    float s = 0.f;
    for (int c = 0; c < 64; ++c) s += ldS(g2W, fw, t * 64 + c) * ldS(ffW, fw, 64 + c);
    w2g[t] = s;
  }
  if (t == 0) {
    float s = ldS(ffb, fw, 0);
    for (int c = 0; c < 64; ++c) {
      s += ldS(f2b, fw, c) * ldS(ffW, fw, c);
      s += ldS(g2b, fw, c) * ldS(ffW, fw, 64 + c);
    }
    constv[0] = s;
  }
}

// ---------------------------------------------------------------------------
// h1s = dinv[i] * (x @ gcn1_W)[i]  (pre-scaled so aggregation needs raw w only).
// 512 threads / 8 waves per 64-node block: wave w owns c-tile (w&3)*16 x
// node-half (w>>2)*32 (acc 8 regs).
// ---------------------------------------------------------------------------
__global__ __launch_bounds__(512, 2) void k_h13u(
    const void* x, const unsigned short* __restrict__ WgT,
    const float* __restrict__ dinv, const int* __restrict__ flags,
    unsigned short* __restrict__ h1b) {
  __shared__ __align__(16) unsigned short Bs[64 * BROW];
  const int nb = blockIdx.x * 64;
  if (flags[0]) stageB8<1>(x, nb, Bs);
  else          stageB8<0>(x, nb, Bs);
  __syncthreads();

  const int lane = threadIdx.x & 63;
  const int wave = threadIdx.x >> 6;
  const int ct = wave & 3;        // c-tile (16 cols)
  const int nh = wave >> 2;       // node half (32 nodes)
  const int l15 = lane & 15;
  const int quad = lane >> 4;
  const unsigned short* ap = WgT + (size_t)(ct * 16 + l15) * 256 + quad * 8;

  f32x4 acc[2];
  acc[0] = (f32x4){0.f, 0.f, 0.f, 0.f};
  acc[1] = (f32x4){0.f, 0.f, 0.f, 0.f};

#pragma unroll
  for (int ks = 0; ks < 8; ++ks) {
    bfrag8 a = *(const bfrag8*)(ap + ks * 32);
    const int bofs = ks * 32 + quad * 8;
#pragma unroll
    for (int u = 0; u < 2; ++u) {
      bfrag8 b = *(const bfrag8*)(Bs + (nh * 32 + u * 16 + l15) * BROW + bofs);
      acc[u] = __builtin_amdgcn_mfma_f32_16x16x32_bf16(a, b, acc[u], 0, 0, 0);
    }
  }
#pragma unroll
  for (int u = 0; u < 2; ++u) {
    int node = nb + nh * 32 + u * 16 + l15;
    if (node < N_NODES) {
      float di = dinv[node];
      us4 o;
#pragma unroll
      for (int r = 0; r < 4; ++r) o[r] = f2bf(acc[u][r] * di);
      *(us4*)(h1b + (size_t)node * 64 + ct * 16 + quad * 4) = o;
    }
  }
}

// ---------------------------------------------------------------------------
// mlpc = folded MLP branch. 8 waves cover all 512 c of the block's 64 nodes ->
// combine wave partials through LDS (reusing Bs) and store mlpc PLAIN
// (no atomics, no zero-init needed).
// ---------------------------------------------------------------------------
__global__ __launch_bounds__(512, 2) void k_mlpu(
    const void* uf, const unsigned short* __restrict__ W1T,
    const void* fc1b, const float* __restrict__ w2f,
    const int* __restrict__ flags, float* __restrict__ mlpc) {
  __shared__ __align__(16) unsigned short Bs[64 * BROW];
  const int nb = blockIdx.x * 64;
  if (flags[2]) stageB8<1>(uf, nb, Bs);
  else          stageB8<0>(uf, nb, Bs);
  __syncthreads();

  const int fw = flags[3];
  const int lane = threadIdx.x & 63;
  const int wave = threadIdx.x >> 6;
  const int l15 = lane & 15;
  const int quad = lane >> 4;
  const int c_base = wave * 64;
  const unsigned short* ap = W1T + (size_t)(c_base + l15) * 256 + quad * 8;

  f32x4 acc[4][4];
#pragma unroll
  for (int t = 0; t < 4; ++t)
#pragma unroll
    for (int u = 0; u < 4; ++u) acc[t][u] = (f32x4){0.f, 0.f, 0.f, 0.f};

#pragma unroll
  for (int ks = 0; ks < 8; ++ks) {
    const int bofs = ks * 32 + quad * 8;
    bfrag8 b[4];
#pragma unroll
    for (int u = 0; u < 4; ++u)
      b[u] = *(const bfrag8*)(Bs + (u * 16 + l15) * BROW + bofs);
#pragma unroll
    for (int t = 0; t < 4; ++t) {
      bfrag8 a = *(const bfrag8*)(ap + (size_t)t * 16 * 256 + ks * 32);
#pragma unroll
      for (int u = 0; u < 4; ++u)
        acc[t][u] = __builtin_amdgcn_mfma_f32_16x16x32_bf16(a, b[u], acc[t][u], 0, 0, 0);
    }
  }
  __syncthreads();   // Bs MFMA reads done; safe to reuse as reduction scratch

  float part[4] = {0.f, 0.f, 0.f, 0.f};
#pragma unroll
  for (int t = 0; t < 4; ++t) {
#pragma unroll
    for (int r = 0; r < 4; ++r) {
      const int c = c_base + t * 16 + quad * 4 + r;
      const float bc = ldS(fc1b, fw, c);
      const float wc = w2f[c];
#pragma unroll
      for (int u = 0; u < 4; ++u) {
        float v = acc[t][u][r] + bc;
        v = v > 0.f ? v : 0.f;
        part[u] += v * wc;
      }
    }
  }
  float* red = (float*)Bs;   // [8][64]
#pragma unroll
  for (int u = 0; u < 4; ++u) {
    part[u] += __shfl_xor(part[u], 16, 64);
    part[u] += __shfl_xor(part[u], 32, 64);
    if (lane < 16) red[wave * 64 + u * 16 + l15] = part[u];
  }
  __syncthreads();
  const int t = threadIdx.x;
  if (t < 64) {
    float sum = 0.f;
#pragma unroll
    for (int w = 0; w < 8; ++w) sum += red[w * 64 + t];
    int node = nb + t;
    if (node < N_NODES) mlpc[node] = sum;
  }
}

// Fused layer-1 aggregation + layer-2 input projection (8-edge unroll).
// h1b holds h1s = dinv*h1, so: g_pre = di*(sum_e w*h1s[s] + h1s[i]) + b1.
// Writes s2s[i] = dinv[i] * (relu(g_pre) . w2g).
__global__ __launch_bounds__(256) void k_aggs2(
    const int* __restrict__ rp, const unsigned long long* __restrict__ e8,
    const unsigned short* __restrict__ h1b, const float* __restrict__ dinv,
    const void* g1b, const float* __restrict__ w2g,
    const int* __restrict__ flags, float* __restrict__ s2) {
  const int i = blockIdx.x * 4 + (threadIdx.x >> 6);
  if (i >= N_NODES) return;
  const int lane = threadIdx.x & 63;
  const int base = rp[i], end = rp[i + 1];
  const float di = dinv[i];
  float acc = 0.f;
  int j = base;
  for (; j + 8 <= end; j += 8) {
    unsigned long long vv[8];
#pragma unroll
    for (int q = 0; q < 8; ++q) vv[q] = e8[j + q];
    float ww[8], hv[8];
#pragma unroll
    for (int q = 0; q < 8; ++q) {
      ww[q] = __uint_as_float((unsigned int)(vv[q] >> 32));
      hv[q] = bf2f(h1b[(size_t)(unsigned int)vv[q] * 64 + lane]);
    }
#pragma unroll
    for (int q = 0; q < 8; ++q) acc += ww[q] * hv[q];
  }
  for (; j < end; ++j) {
    unsigned long long v = e8[j];
    acc += __uint_as_float((unsigned int)(v >> 32)) *
           bf2f(h1b[(size_t)(unsigned int)v * 64 + lane]);
  }
  float v = (acc + bf2f(h1b[(size_t)i * 64 + lane])) * di + ldS(g1b, flags[3], lane);
  v = v > 0.f ? v : 0.f;
  float p = v * w2g[lane];
#pragma unroll
  for (int off = 32; off > 0; off >>= 1) p += __shfl_xor(p, off, 64);
  if (lane == 0) s2[i] = di * p;
}

// Fused layer-2 aggregation + final output. s2 holds s2s = dinv*s2_raw, so:
// gnn_term = di*(sum_e w*s2s[s] + s2s[i]).
__global__ __launch_bounds__(256) void k_fin2(
    const int* __restrict__ rp, const unsigned long long* __restrict__ e8,
    const float* __restrict__ s2, const float* __restrict__ dinv,
    const float* __restrict__ mlpc, const float* __restrict__ constv,
    const int* __restrict__ flags, void* out) {
  const int i = blockIdx.x * 4 + (threadIdx.x >> 6);
  if (i >= N_NODES) return;
  const int lane = threadIdx.x & 63;
  const int base = rp[i], end = rp[i + 1];
  float p = 0.f;
  for (int j = base + lane; j < end; j += 64) {
    unsigned long long v = e8[j];
    p += __uint_as_float((unsigned int)(v >> 32)) * s2[(unsigned int)v];
  }
#pragma unroll
  for (int off = 32; off > 0; off >>= 1) p += __shfl_xor(p, off, 64);
  if (lane == 0) {
    float di = dinv[i];
    stO(out, flags[5], i, mlpc[i] + di * (p + s2[i]) + constv[0]);
  }
}

__global__ __launch_bounds__(256) void k_zero(const int* __restrict__ flags, void* out) {
  int i = blockIdx.x * 256 + threadIdx.x;
  if (i < N_NODES) stO(out, flags[5], i, 0.f);
}

extern "C" void kernel_launch(void* const* d_in, const int* in_sizes, int n_in,
                              void* d_out, int out_size, void* d_ws, size_t ws_size,
                              hipStream_t stream) {
  const void* x   = d_in[0];
  const int*  ei  = (const int*)d_in[1];
  const void* ea  = d_in[2];
  const void* uf  = d_in[3];
  const void* g1W = d_in[4];
  const void* g1b = d_in[5];
  const void* g2W = d_in[6];
  const void* g2b = d_in[7];
  const void* f1W = d_in[8];
  const void* f1b = d_in[9];
  const void* f2W = d_in[10];
  const void* f2b = d_in[11];
  const void* ffW = d_in[12];
  const void* ffb = d_in[13];

  float* ws = (float*)d_ws;
  int*   flags  = (int*)ws;                 // 16
  float* w2f    = ws + 16;                  // 512
  float* w2g    = ws + 528;                 // 64
  float* constv = ws + 592;                 // 16
  float* dinv   = ws + 608;                 // 50,000
  float* s2     = ws + 50608;               // 50,000
  float* mlpc   = ws + 100608;              // 50,000
  unsigned short* W1T = (unsigned short*)(ws + 150608);  // 131,072 us
  unsigned short* WgT = W1T + 131072;                    // 16,384 us
  int* rowptr = (int*)(ws + 224336);        // 50,001 (pad 16)
  int* bsum   = (int*)(ws + 274352);        // 64
  int* boff   = bsum + 64;                  // 64
  int* counts = (int*)(ws + 274480);        // 50,016
  int* posw   = (int*)(ws + 324496);        // 800,000
  unsigned long long* e8 = (unsigned long long*)(ws + 1124496); // 800,000 x 8B
  unsigned short* h1b = (unsigned short*)(ws + 2724496); // 3.2M us
  const size_t NEED = (size_t)4324496 * 4;  // ~17.3 MB

  k_detect<<<1, 64, 0, stream>>>(x, ea, uf, f1W, ei, flags);
  if (ws_size < NEED) {
    k_zero<<<(N_NODES + 255) / 256, 256, 0, stream>>>(flags, d_out);
    return;
  }
  const int NZB = (N_NODES + 256) / 256;    // covers N_NODES+1
  const int NB  = (N_NODES + 1023) / 1024;  // 49
  const int NGB = (N_NODES + 63) / 64;      // 782
  const int NEB = (N_EDGES + 255) / 256;    // 3125

  k_zeroc<<<NZB, 256, 0, stream>>>(counts);
  k_histpos<<<NEB, 256, 0, stream>>>(ei, flags, counts, posw);
  k_scan1<<<NB, 256, 0, stream>>>(counts, rowptr, bsum);
  k_scan2<<<1, 64, 0, stream>>>(bsum, boff, rowptr, NB);
  k_scan3<<<(N_NODES + 255) / 256, 256, 0, stream>>>(rowptr, boff);
  k_placeb<<<NEB, 256, 0, stream>>>(ei, ea, flags, rowptr, posw, e8);
  k_degc<<<(N_NODES + 3) / 4, 256, 0, stream>>>(rowptr, e8, dinv);
  k_prep<<<289, 512, 0, stream>>>(f1W, g1W, f2W, f2b, g2W, g2b, ffW, ffb, flags,
                                  W1T, WgT, w2f, w2g, constv);
  k_h13u<<<NGB, 512, 0, stream>>>(x, WgT, dinv, flags, h1b);
  k_mlpu<<<NGB, 512, 0, stream>>>(uf, W1T, f1b, w2f, flags, mlpc);
  k_aggs2<<<(N_NODES + 3) / 4, 256, 0, stream>>>(rowptr, e8, h1b, dinv, g1b, w2g, flags, s2);
  k_fin2<<<(N_NODES + 3) / 4, 256, 0, stream>>>(rowptr, e8, s2, dinv, mlpc, constv, flags, d_out);
}

// Round 3
// 352.318 us; speedup vs baseline: 1.1724x; 1.0225x over previous
//
#include <hip/hip_runtime.h>
#include <hip/hip_bf16.h>

#define N_NODES 50000
#define N_EDGES 800000
#define BROW 264       // padded LDS row stride in us (528 B)
#define NT_TILES 782   // ceil(50000/64)
#define GRID_MLP 256
#define GRID_H13 512

typedef __attribute__((ext_vector_type(8))) short bfrag8;   // 8 bf16 (4 VGPRs)
typedef __attribute__((ext_vector_type(4))) float f32x4;
typedef __attribute__((ext_vector_type(4))) unsigned short us4;
typedef __attribute__((ext_vector_type(8))) unsigned short us8;

__device__ __forceinline__ float bf2f(unsigned short u) {
  return __uint_as_float(((unsigned int)u) << 16);
}
__device__ __forceinline__ unsigned short f2bf(float f) {
  unsigned int u = __float_as_uint(f);
  u = (u + 0x7fffu + ((u >> 16) & 1u)) >> 16;
  return (unsigned short)u;
}
__device__ __forceinline__ float ldS(const void* p, int f32, size_t i) {
  return f32 ? ((const float*)p)[i] : bf2f(((const unsigned short*)p)[i]);
}
__device__ __forceinline__ void stO(void* out, int f32, int i, float v) {
  if (f32) ((float*)out)[i] = v;
  else ((unsigned short*)out)[i] = f2bf(v);
}

// ---- staging (512 threads, 64 rows x 256 cols -> bf16 LDS tile) ----------
// Mapping row=t&63, chunk=t>>6: ds_write groups (r+4q+j)%8 -> lanes 0..7
// cover all 8 LDS 16B bank-groups => conflict-free writes (old t>>3 mapping
// hit 2 groups -> 4-way conflict, 1.4M cycles/dispatch).
__device__ __forceinline__ void stageLoadBF(const void* src, int nb, us8 st[4]) {
  const int t = threadIdx.x;
  const int r = t & 63, q = t >> 6;
  int row = nb + r; row = row < N_NODES ? row : (N_NODES - 1);
  const us8* s8 = (const us8*)((const unsigned short*)src + (size_t)row * 256 + q * 32);
#pragma unroll
  for (int j = 0; j < 4; ++j) st[j] = s8[j];
}
__device__ __forceinline__ void stageWrite(const us8 st[4], unsigned short* __restrict__ Bs) {
  const int t = threadIdx.x;
  const int r = t & 63, q = t >> 6;
  unsigned short* dst = Bs + r * BROW + q * 32;
#pragma unroll
  for (int j = 0; j < 4; ++j) *(us8*)(dst + j * 8) = st[j];
}
__device__ __forceinline__ void stageF32(const void* src, int nb,
                                         unsigned short* __restrict__ Bs) {
  const int t = threadIdx.x;
  const int r = t & 63, q = t >> 6;
  int row = nb + r; row = row < N_NODES ? row : (N_NODES - 1);
  const f32x4* s4 = (const f32x4*)((const float*)src + (size_t)row * 256 + q * 32);
  unsigned short* dst = Bs + r * BROW + q * 32;
#pragma unroll
  for (int j = 0; j < 4; ++j) {
    f32x4 a = s4[2 * j], b = s4[2 * j + 1];
    us8 o;
    o[0] = f2bf(a[0]); o[1] = f2bf(a[1]); o[2] = f2bf(a[2]); o[3] = f2bf(a[3]);
    o[4] = f2bf(b[0]); o[5] = f2bf(b[1]); o[6] = f2bf(b[2]); o[7] = f2bf(b[3]);
    *(us8*)(dst + j * 8) = o;
  }
}

// flags: 0=x_is_f32 1=ea_is_f32 2=uf_is_f32 3=W_is_f32 4=idx_is_i64 5=out_is_f32
__global__ void k_detect(const void* x, const void* ea, const void* uf,
                         const void* f1W, const int* ei, int* flags) {
  int lane = threadIdx.x & 63;
  unsigned short ux = ((const unsigned short*)x)[lane];
  unsigned short ue = ((const unsigned short*)ea)[lane];
  unsigned short uu = ((const unsigned short*)uf)[lane];
  unsigned short uw = ((const unsigned short*)f1W)[lane];
  int oi = ei[2 * lane + 1];
  unsigned long long bx = __ballot(((ux >> 7) & 0xFF) > 0x85);
  unsigned long long be = __ballot((ue & 0x8000u) != 0);
  unsigned long long bu = __ballot(((uu >> 7) & 0xFF) > 0x85);
  unsigned long long bw = __ballot(((uw >> 7) & 0xFF) > 0x7E);
  unsigned long long bi = __ballot(oi != 0);
  if (lane == 0) {
    int fx = bx ? 1 : 0, fe = be ? 1 : 0, fu = bu ? 1 : 0, fw = bw ? 1 : 0;
    flags[0] = fx; flags[1] = fe; flags[2] = fu; flags[3] = fw;
    flags[4] = (bi == 0ull) ? 1 : 0;
    flags[5] = (fx & fe & fu & fw);
  }
}

__global__ __launch_bounds__(256) void k_zeroc(int* __restrict__ counts) {
  int i = blockIdx.x * 256 + threadIdx.x;
  if (i <= N_NODES) counts[i] = 0;
}

// Histogram of dst + record each edge's within-segment position.
__global__ __launch_bounds__(256) void k_histpos(const int* __restrict__ ei,
                                                 const int* __restrict__ flags,
                                                 int* __restrict__ counts,
                                                 int* __restrict__ posw) {
  int e = blockIdx.x * 256 + threadIdx.x;
  if (e >= N_EDGES) return;
  int d;
  if (flags[4]) d = ei[1600000 + 2 * e];
  else          d = ei[800000 + e];
  d = d < 0 ? 0 : (d > N_NODES - 1 ? N_NODES - 1 : d);
  posw[e] = atomicAdd(&counts[d], 1);
}

__global__ __launch_bounds__(256) void k_scan1(const int* __restrict__ cnt,
                                               int* __restrict__ rp,
                                               int* __restrict__ bsum) {
  __shared__ int sd[256];
  int t = threadIdx.x;
  int i0 = blockIdx.x * 1024 + t * 4;
  int v0 = (i0 + 0) < N_NODES ? cnt[i0 + 0] : 0;
  int v1 = (i0 + 1) < N_NODES ? cnt[i0 + 1] : 0;
  int v2 = (i0 + 2) < N_NODES ? cnt[i0 + 2] : 0;
  int v3 = (i0 + 3) < N_NODES ? cnt[i0 + 3] : 0;
  int ts = v0 + v1 + v2 + v3;
  sd[t] = ts;
  __syncthreads();
  for (int off = 1; off < 256; off <<= 1) {
    int x = (t >= off) ? sd[t - off] : 0;
    __syncthreads();
    sd[t] += x;
    __syncthreads();
  }
  int exoff = sd[t] - ts;
  if (i0 + 0 < N_NODES) rp[i0 + 0] = exoff;
  if (i0 + 1 < N_NODES) rp[i0 + 1] = exoff + v0;
  if (i0 + 2 < N_NODES) rp[i0 + 2] = exoff + v0 + v1;
  if (i0 + 3 < N_NODES) rp[i0 + 3] = exoff + v0 + v1 + v2;
  if (t == 255) bsum[blockIdx.x] = sd[255];
}

__global__ void k_scan2(const int* __restrict__ bsum, int* __restrict__ boff,
                        int* __restrict__ rp, int nb) {
  if (threadIdx.x == 0) {
    int run = 0;
    for (int b = 0; b < nb; ++b) { boff[b] = run; run += bsum[b]; }
    rp[N_NODES] = run;
  }
}

__global__ __launch_bounds__(256) void k_scan3(int* __restrict__ rp,
                                               const int* __restrict__ boff) {
  int i = blockIdx.x * 256 + threadIdx.x;
  if (i < N_NODES) rp[i] += boff[i >> 10];
}

// Atomic-free CSR scatter: pos = rowptr[d] + posw[e]; packed {w:hi32, s:lo32}.
__global__ __launch_bounds__(256) void k_placeb(const int* __restrict__ ei,
                                                const void* ea,
                                                const int* __restrict__ flags,
                                                const int* __restrict__ rp,
                                                const int* __restrict__ posw,
                                                unsigned long long* __restrict__ e8) {
  int e = blockIdx.x * 256 + threadIdx.x;
  if (e >= N_EDGES) return;
  int s, d;
  if (flags[4]) { s = ei[2 * e]; d = ei[1600000 + 2 * e]; }
  else          { s = ei[e];     d = ei[800000 + e]; }
  s = s < 0 ? 0 : (s > N_NODES - 1 ? N_NODES - 1 : s);
  d = d < 0 ? 0 : (d > N_NODES - 1 ? N_NODES - 1 : d);
  float w = ldS(ea, flags[1], e);
  int pos = rp[d] + posw[e];
  e8[pos] = ((unsigned long long)__float_as_uint(w) << 32) | (unsigned int)s;
}

// Weighted degree via coalesced CSR walk; dinv = rsqrt(deg + 1).
__global__ __launch_bounds__(256) void k_degc(const int* __restrict__ rp,
                                              const unsigned long long* __restrict__ e8,
                                              float* __restrict__ dinv) {
  const int i = blockIdx.x * 4 + (threadIdx.x >> 6);
  if (i >= N_NODES) return;
  const int lane = threadIdx.x & 63;
  const int base = rp[i], end = rp[i + 1];
  float s = 0.f;
  for (int j = base + lane; j < end; j += 64)
    s += __uint_as_float((unsigned int)(e8[j] >> 32));
#pragma unroll
  for (int off = 32; off > 0; off >>= 1) s += __shfl_xor(s, off, 64);
  if (lane == 0) dinv[i] = rsqrtf(s + 1.0f);
}

// Merged: blocks 0..287 transpose W1T/WgT; block 288 computes folded head vectors.
__global__ __launch_bounds__(512) void k_prep(
    const void* f1W, const void* g1W, const void* f2W, const void* f2b,
    const void* g2W, const void* g2b, const void* ffW, const void* ffb,
    const int* __restrict__ flags, unsigned short* __restrict__ W1T,
    unsigned short* __restrict__ WgT, float* __restrict__ w2f,
    float* __restrict__ w2g, float* __restrict__ constv) {
  const int fw = flags[3];
  if (blockIdx.x < 288) {
    int tid = blockIdx.x * 512 + threadIdx.x;
    if (tid < 512 * 256) {
      int c = tid >> 8, k = tid & 255;
      W1T[tid] = f2bf(ldS(f1W, fw, (size_t)k * 512 + c));
    } else if (tid < 512 * 256 + 64 * 256) {
      int j = tid - 512 * 256;
      int c = j >> 8, k = j & 255;
      WgT[j] = f2bf(ldS(g1W, fw, (size_t)k * 64 + c));
    }
    return;
  }
  int t = threadIdx.x;
  if (t < 512) {
    float s = 0.f;
    for (int c = 0; c < 64; ++c) s += ldS(f2W, fw, t * 64 + c) * ldS(ffW, fw, c);
    w2f[t] = s;
  }
  if (t < 64) {
    float s = 0.f;
    for (int c = 0; c < 64; ++c) s += ldS(g2W, fw, t * 64 + c) * ldS(ffW, fw, 64 + c);
    w2g[t] = s;
  }
  if (t == 0) {
    float s = ldS(ffb, fw, 0);
    for (int c = 0; c < 64; ++c) {
      s += ldS(f2b, fw, c) * ldS(ffW, fw, c);
      s += ldS(g2b, fw, c) * ldS(ffW, fw, 64 + c);
    }
    constv[0] = s;
  }
}

// ---------------------------------------------------------------------------
// h1s = dinv[i] * (x @ gcn1_W)[i]. Persistent-A: wave holds its 16-c A-panel
// in 8 bfrag8 (32 VGPRs) for the whole kernel; grid-stride over node tiles
// with double-buffered LDS B and deferred (load->compute->write) staging.
// ---------------------------------------------------------------------------
__global__ __launch_bounds__(512, 2) void k_h13P(
    const void* x, const unsigned short* __restrict__ WgT,
    const float* __restrict__ dinv, const int* __restrict__ flags,
    unsigned short* __restrict__ h1b) {
  __shared__ __align__(16) unsigned short Bs[2][64 * BROW];
  const int f32in = flags[0];
  const int lane = threadIdx.x & 63;
  const int wave = threadIdx.x >> 6;
  const int ct = wave & 3;        // c-tile (16 cols)
  const int nh = wave >> 2;       // node half (32 nodes)
  const int l15 = lane & 15;
  const int quad = lane >> 4;

  // A-panel resident in registers (loaded once).
  bfrag8 A[8];
  {
    const unsigned short* ap = WgT + (size_t)(ct * 16 + l15) * 256 + quad * 8;
#pragma unroll
    for (int ks = 0; ks < 8; ++ks) A[ks] = *(const bfrag8*)(ap + ks * 32);
  }

  int tile = blockIdx.x;
  if (f32in) stageF32(x, tile * 64, Bs[0]);
  else { us8 st[4]; stageLoadBF(x, tile * 64, st); stageWrite(st, Bs[0]); }
  __syncthreads();

  int cur = 0;
  for (; tile < NT_TILES; tile += GRID_H13) {
    const int nxt = tile + GRID_H13;
    const bool have = nxt < NT_TILES;
    us8 st[4];
    if (!f32in && have) stageLoadBF(x, nxt * 64, st);   // issue early

    f32x4 acc[2];
    acc[0] = (f32x4){0.f, 0.f, 0.f, 0.f};
    acc[1] = (f32x4){0.f, 0.f, 0.f, 0.f};
    const unsigned short* Bc = Bs[cur];
#pragma unroll
    for (int ks = 0; ks < 8; ++ks) {
      const int bofs = ks * 32 + quad * 8;
#pragma unroll
      for (int u = 0; u < 2; ++u) {
        bfrag8 b = *(const bfrag8*)(Bc + (nh * 32 + u * 16 + l15) * BROW + bofs);
        acc[u] = __builtin_amdgcn_mfma_f32_16x16x32_bf16(A[ks], b, acc[u], 0, 0, 0);
      }
    }

    if (have) {
      if (f32in) stageF32(x, nxt * 64, Bs[cur ^ 1]);
      else       stageWrite(st, Bs[cur ^ 1]);
    }

#pragma unroll
    for (int u = 0; u < 2; ++u) {
      int node = tile * 64 + nh * 32 + u * 16 + l15;
      if (node < N_NODES) {
        float di = dinv[node];
        us4 o;
#pragma unroll
        for (int r = 0; r < 4; ++r) o[r] = f2bf(acc[u][r] * di);
        *(us4*)(h1b + (size_t)node * 64 + ct * 16 + quad * 4) = o;
      }
    }
    __syncthreads();   // all reads of Bs[cur] done; Bs[cur^1] staged
    cur ^= 1;
  }
}

// ---------------------------------------------------------------------------
// mlpc = folded MLP branch, persistent-A. Wave holds its 64-c A-panel in
// 32 bfrag8 (128 VGPRs); acc in AGPRs. Grid = 256 (1 block/CU), ~3 tiles each.
// Kills the per-block serialized W1T L2-latency chain (782x -> 256x reads,
// off critical path) that pinned the old kernel at MfmaUtil 8.6%.
// ---------------------------------------------------------------------------
__global__ __launch_bounds__(512, 2) void k_mlpP(
    const void* uf, const unsigned short* __restrict__ W1T,
    const void* fc1b, const float* __restrict__ w2f,
    const int* __restrict__ flags, float* __restrict__ mlpc) {
  __shared__ __align__(16) unsigned short Bs[2][64 * BROW];
  __shared__ float red[2][512];
  const int f32in = flags[2];
  const int fw = flags[3];
  const int lane = threadIdx.x & 63;
  const int wave = threadIdx.x >> 6;
  const int l15 = lane & 15;
  const int quad = lane >> 4;
  const int c_base = wave * 64;

  // A-panel resident in registers: 4 c-subtiles x 8 k-slices = 128 VGPRs.
  bfrag8 A[4][8];
  {
    const unsigned short* ap = W1T + (size_t)(c_base + l15) * 256 + quad * 8;
#pragma unroll
    for (int t = 0; t < 4; ++t)
#pragma unroll
      for (int ks = 0; ks < 8; ++ks)
        A[t][ks] = *(const bfrag8*)(ap + (size_t)t * 16 * 256 + ks * 32);
  }

  int tile = blockIdx.x;
  if (f32in) stageF32(uf, tile * 64, Bs[0]);
  else { us8 st[4]; stageLoadBF(uf, tile * 64, st); stageWrite(st, Bs[0]); }
  __syncthreads();

  int cur = 0, pp = 0;
  for (; tile < NT_TILES; tile += GRID_MLP) {
    const int nxt = tile + GRID_MLP;
    const bool have = nxt < NT_TILES;
    us8 st[4];
    if (!f32in && have) stageLoadBF(uf, nxt * 64, st);   // issue early

    f32x4 acc[4][4];
#pragma unroll
    for (int t = 0; t < 4; ++t)
#pragma unroll
      for (int u = 0; u < 4; ++u) acc[t][u] = (f32x4){0.f, 0.f, 0.f, 0.f};

    const unsigned short* Bc = Bs[cur];
#pragma unroll
    for (int ks = 0; ks < 8; ++ks) {
      const int bofs = ks * 32 + quad * 8;
      bfrag8 b[4];
#pragma unroll
      for (int u = 0; u < 4; ++u)
        b[u] = *(const bfrag8*)(Bc + (u * 16 + l15) * BROW + bofs);
#pragma unroll
      for (int t = 0; t < 4; ++t)
#pragma unroll
        for (int u = 0; u < 4; ++u)
          acc[t][u] = __builtin_amdgcn_mfma_f32_16x16x32_bf16(A[t][ks], b[u], acc[t][u], 0, 0, 0);
    }

    // fold: relu(acc + bias) . w2f, partial per node
    float part[4] = {0.f, 0.f, 0.f, 0.f};
#pragma unroll
    for (int t = 0; t < 4; ++t) {
#pragma unroll
      for (int r = 0; r < 4; ++r) {
        const int c = c_base + t * 16 + quad * 4 + r;
        const float bc = ldS(fc1b, fw, c);
        const float wc = w2f[c];
#pragma unroll
        for (int u = 0; u < 4; ++u) {
          float v = acc[t][u][r] + bc;
          v = v > 0.f ? v : 0.f;
          part[u] += v * wc;
        }
      }
    }

    if (have) {
      if (f32in) stageF32(uf, nxt * 64, Bs[cur ^ 1]);
      else       stageWrite(st, Bs[cur ^ 1]);
    }

#pragma unroll
    for (int u = 0; u < 4; ++u) {
      part[u] += __shfl_xor(part[u], 16, 64);
      part[u] += __shfl_xor(part[u], 32, 64);
      if (lane < 16) red[pp][wave * 64 + u * 16 + l15] = part[u];
    }
    __syncthreads();   // red complete; Bs[cur] reads done; Bs[cur^1] staged
    if (threadIdx.x < 64) {
      float sum = 0.f;
#pragma unroll
      for (int w = 0; w < 8; ++w) sum += red[pp][w * 64 + threadIdx.x];
      int node = tile * 64 + threadIdx.x;
      if (node < N_NODES) mlpc[node] = sum;
    }
    cur ^= 1; pp ^= 1;
  }
}

// Fused layer-1 aggregation + layer-2 input projection (8-edge unroll).
__global__ __launch_bounds__(256) void k_aggs2(
    const int* __restrict__ rp, const unsigned long long* __restrict__ e8,
    const unsigned short* __restrict__ h1b, const float* __restrict__ dinv,
    const void* g1b, const float* __restrict__ w2g,
    const int* __restrict__ flags, float* __restrict__ s2) {
  const int i = blockIdx.x * 4 + (threadIdx.x >> 6);
  if (i >= N_NODES) return;
  const int lane = threadIdx.x & 63;
  const int base = rp[i], end = rp[i + 1];
  const float di = dinv[i];
  float acc = 0.f;
  int j = base;
  for (; j + 8 <= end; j += 8) {
    unsigned long long vv[8];
#pragma unroll
    for (int q = 0; q < 8; ++q) vv[q] = e8[j + q];
    float ww[8], hv[8];
#pragma unroll
    for (int q = 0; q < 8; ++q) {
      ww[q] = __uint_as_float((unsigned int)(vv[q] >> 32));
      hv[q] = bf2f(h1b[(size_t)(unsigned int)vv[q] * 64 + lane]);
    }
#pragma unroll
    for (int q = 0; q < 8; ++q) acc += ww[q] * hv[q];
  }
  for (; j < end; ++j) {
    unsigned long long v = e8[j];
    acc += __uint_as_float((unsigned int)(v >> 32)) *
           bf2f(h1b[(size_t)(unsigned int)v * 64 + lane]);
  }
  float v = (acc + bf2f(h1b[(size_t)i * 64 + lane])) * di + ldS(g1b, flags[3], lane);
  v = v > 0.f ? v : 0.f;
  float p = v * w2g[lane];
#pragma unroll
  for (int off = 32; off > 0; off >>= 1) p += __shfl_xor(p, off, 64);
  if (lane == 0) s2[i] = di * p;
}

// Fused layer-2 aggregation + final output.
__global__ __launch_bounds__(256) void k_fin2(
    const int* __restrict__ rp, const unsigned long long* __restrict__ e8,
    const float* __restrict__ s2, const float* __restrict__ dinv,
    const float* __restrict__ mlpc, const float* __restrict__ constv,
    const int* __restrict__ flags, void* out) {
  const int i = blockIdx.x * 4 + (threadIdx.x >> 6);
  if (i >= N_NODES) return;
  const int lane = threadIdx.x & 63;
  const int base = rp[i], end = rp[i + 1];
  float p = 0.f;
  for (int j = base + lane; j < end; j += 64) {
    unsigned long long v = e8[j];
    p += __uint_as_float((unsigned int)(v >> 32)) * s2[(unsigned int)v];
  }
#pragma unroll
  for (int off = 32; off > 0; off >>= 1) p += __shfl_xor(p, off, 64);
  if (lane == 0) {
    float di = dinv[i];
    stO(out, flags[5], i, mlpc[i] + di * (p + s2[i]) + constv[0]);
  }
}

__global__ __launch_bounds__(256) void k_zero(const int* __restrict__ flags, void* out) {
  int i = blockIdx.x * 256 + threadIdx.x;
  if (i < N_NODES) stO(out, flags[5], i, 0.f);
}

extern "C" void kernel_launch(void* const* d_in, const int* in_sizes, int n_in,
                              void* d_out, int out_size, void* d_ws, size_t ws_size,
                              hipStream_t stream) {
  const void* x   = d_in[0];
  const int*  ei  = (const int*)d_in[1];
  const void* ea  = d_in[2];
  const void* uf  = d_in[3];
  const void* g1W = d_in[4];
  const void* g1b = d_in[5];
  const void* g2W = d_in[6];
  const void* g2b = d_in[7];
  const void* f1W = d_in[8];
  const void* f1b = d_in[9];
  const void* f2W = d_in[10];
  const void* f2b = d_in[11];
  const void* ffW = d_in[12];
  const void* ffb = d_in[13];

  float* ws = (float*)d_ws;
  int*   flags  = (int*)ws;                 // 16
  float* w2f    = ws + 16;                  // 512
  float* w2g    = ws + 528;                 // 64
  float* constv = ws + 592;                 // 16
  float* dinv   = ws + 608;                 // 50,000
  float* s2     = ws + 50608;               // 50,000
  float* mlpc   = ws + 100608;              // 50,000
  unsigned short* W1T = (unsigned short*)(ws + 150608);  // 131,072 us
  unsigned short* WgT = W1T + 131072;                    // 16,384 us
  int* rowptr = (int*)(ws + 224336);        // 50,001 (pad 16)
  int* bsum   = (int*)(ws + 274352);        // 64
  int* boff   = bsum + 64;                  // 64
  int* counts = (int*)(ws + 274480);        // 50,016
  int* posw   = (int*)(ws + 324496);        // 800,000
  unsigned long long* e8 = (unsigned long long*)(ws + 1124496); // 800,000 x 8B
  unsigned short* h1b = (unsigned short*)(ws + 2724496); // 3.2M us
  const size_t NEED = (size_t)4324496 * 4;  // ~17.3 MB

  k_detect<<<1, 64, 0, stream>>>(x, ea, uf, f1W, ei, flags);
  if (ws_size < NEED) {
    k_zero<<<(N_NODES + 255) / 256, 256, 0, stream>>>(flags, d_out);
    return;
  }
  const int NZB = (N_NODES + 256) / 256;    // covers N_NODES+1
  const int NB  = (N_NODES + 1023) / 1024;  // 49
  const int NEB = (N_EDGES + 255) / 256;    // 3125

  k_zeroc<<<NZB, 256, 0, stream>>>(counts);
  k_histpos<<<NEB, 256, 0, stream>>>(ei, flags, counts, posw);
  k_scan1<<<NB, 256, 0, stream>>>(counts, rowptr, bsum);
  k_scan2<<<1, 64, 0, stream>>>(bsum, boff, rowptr, NB);
  k_scan3<<<(N_NODES + 255) / 256, 256, 0, stream>>>(rowptr, boff);
  k_placeb<<<NEB, 256, 0, stream>>>(ei, ea, flags, rowptr, posw, e8);
  k_degc<<<(N_NODES + 3) / 4, 256, 0, stream>>>(rowptr, e8, dinv);
  k_prep<<<289, 512, 0, stream>>>(f1W, g1W, f2W, f2b, g2W, g2b, ffW, ffb, flags,
                                  W1T, WgT, w2f, w2g, constv);
  k_h13P<<<GRID_H13, 512, 0, stream>>>(x, WgT, dinv, flags, h1b);
  k_mlpP<<<GRID_MLP, 512, 0, stream>>>(uf, W1T, f1b, w2f, flags, mlpc);
  k_aggs2<<<(N_NODES + 3) / 4, 256, 0, stream>>>(rowptr, e8, h1b, dinv, g1b, w2g, flags, s2);
  k_fin2<<<(N_NODES + 3) / 4, 256, 0, stream>>>(rowptr, e8, s2, dinv, mlpc, constv, flags, d_out);
}